// Round 5
// baseline (422.262 us; speedup 1.0000x reference)
//
#include <hip/hip_runtime.h>
#include <math.h>

// Problem constants (fixed shapes from setup_inputs)
constexpr int TOPK = 8;
constexpr int NUM_SPECIAL = 999;
constexpr int V = 30522;
constexpr int D = 768;
constexpr int BLOCK = 256;
constexpr int V2 = V / 2;          // 15261 float2 per row (V even, rows 8B-aligned)
constexpr int NSLICE = 4;          // slices per row; f2 counts {3816,3815,3815,3815}
constexpr int NL = 15;             // max float2 per thread within a slice
constexpr int CAP = 256;           // per-slice candidate bound (ties safety)

// Monotone map float -> uint32 (order-preserving), packed with ~idx so that
// larger key == (larger value, then SMALLER index) -- matches jax.lax.top_k
// tie-breaking (lower index first among equal values).
__device__ __forceinline__ unsigned long long fkey(float v, unsigned int idx) {
    unsigned int u = __float_as_uint(v);
    u = ((int)u < 0) ? ~u : (u | 0x80000000u);
    return ((unsigned long long)u << 32) | (unsigned long long)(~idx);
}

__device__ __forceinline__ void cmpx(float& a, float& b) {  // desc compare-exchange
    float m = fmaxf(a, b), n = fminf(a, b); a = m; b = n;
}

// Batcher odd-even mergesort, 8 elements, descending (19 CE)
__device__ __forceinline__ void sort8_desc(float (&c)[8]) {
    cmpx(c[0],c[1]); cmpx(c[2],c[3]); cmpx(c[4],c[5]); cmpx(c[6],c[7]);
    cmpx(c[0],c[2]); cmpx(c[1],c[3]); cmpx(c[1],c[2]);
    cmpx(c[4],c[6]); cmpx(c[5],c[7]); cmpx(c[5],c[6]);
    cmpx(c[0],c[4]); cmpx(c[1],c[5]); cmpx(c[2],c[6]); cmpx(c[3],c[7]);
    cmpx(c[2],c[4]); cmpx(c[3],c[5]);
    cmpx(c[1],c[2]); cmpx(c[3],c[4]); cmpx(c[5],c[6]);
}

// R (sorted desc) <- top-8 of R ∪ C (C sorted desc): half-merge + bitonic re-sort
__device__ __forceinline__ void merge_top8(float (&R)[8], const float (&C)[8]) {
    float m[8];
    #pragma unroll
    for (int j = 0; j < 8; ++j) m[j] = fmaxf(R[j], C[7 - j]);
    cmpx(m[0],m[4]); cmpx(m[1],m[5]); cmpx(m[2],m[6]); cmpx(m[3],m[7]);
    cmpx(m[0],m[2]); cmpx(m[1],m[3]); cmpx(m[4],m[6]); cmpx(m[5],m[7]);
    cmpx(m[0],m[1]); cmpx(m[2],m[3]); cmpx(m[4],m[5]); cmpx(m[6],m[7]);
    #pragma unroll
    for (int j = 0; j < 8; ++j) R[j] = m[j];
}

// Per-wave exact top-8 extraction from 64 sorted-desc 8-lists (pops heads).
__device__ __forceinline__ void wave_extract8(float (&cur)[TOPK], int lane,
                                              float* dst) {
    #pragma unroll
    for (int r = 0; r < TOPK; ++r) {
        float m = cur[0];
        int ml = lane;
        #pragma unroll
        for (int off = 1; off < 64; off <<= 1) {
            float om = __shfl_xor(m, off, 64);
            int   ol = __shfl_xor(ml, off, 64);
            if (om > m || (om == m && ol < ml)) { m = om; ml = ol; }
        }
        if (lane == ml) {
            #pragma unroll
            for (int j = 0; j < TOPK - 1; ++j) cur[j] = cur[j + 1];
            cur[TOPK - 1] = -INFINITY;
        }
        if (lane == 0) dst[r] = m;
    }
}

// ============================ Kernel 1 ======================================
// One block per (row, slice). Slice lives in registers; no memory re-read for
// index recovery. Writes the slice's exact top-8 (value,~idx) keys to ws.
__global__ __launch_bounds__(BLOCK) void topk_slice_kernel(
    const float* __restrict__ pred_lm,              // [B,S,V]
    unsigned long long* __restrict__ ws_keys)       // [B*S][NSLICE][TOPK]
{
    const int row = blockIdx.x >> 2;
    const int s   = blockIdx.x & 3;
    const int tid = threadIdx.x;
    const int lane = tid & 63;
    const int wave = tid >> 6;

    // slice boundaries in float2 units: starts {0,3816,7631,11446}
    const int f2start = (s == 0) ? 0 : (3816 + 3815 * (s - 1));
    const int cnt     = (s == 0) ? 3816 : 3815;

    __shared__ float  sm32[32];
    __shared__ float  s_g8;
    __shared__ int    s_ncand;
    __shared__ unsigned long long sh_cand[CAP];     // 2 KB
    __shared__ unsigned long long s_top[TOPK];

    if (tid == 0) s_ncand = 0;

    // ---- load entire slice chunk into registers (all loads issued up-front)
    const float2* row2 = (const float2*)(pred_lm + (size_t)row * V) + f2start;
    float2 arr[NL];
    #pragma unroll
    for (int k = 0; k < NL; ++k) {
        const int idx = tid + (k << 8);
        float2 v = make_float2(-INFINITY, -INFINITY);
        if (idx < cnt) v = row2[idx];
        arr[k] = v;
    }

    // ---- per-thread exact top-8 values via chunked sort-merge --------------
    float R[8];
    {
        float c[8] = {arr[0].x, arr[0].y, arr[1].x, arr[1].y,
                      arr[2].x, arr[2].y, arr[3].x, arr[3].y};
        sort8_desc(c);
        #pragma unroll
        for (int j = 0; j < 8; ++j) R[j] = c[j];
    }
    {
        float c[8] = {arr[4].x, arr[4].y, arr[5].x, arr[5].y,
                      arr[6].x, arr[6].y, arr[7].x, arr[7].y};
        sort8_desc(c); merge_top8(R, c);
    }
    {
        float c[8] = {arr[8].x, arr[8].y, arr[9].x, arr[9].y,
                      arr[10].x, arr[10].y, arr[11].x, arr[11].y};
        sort8_desc(c); merge_top8(R, c);
    }
    {
        float c[8] = {arr[12].x, arr[12].y, arr[13].x, arr[13].y,
                      arr[14].x, arr[14].y, -INFINITY, -INFINITY};
        sort8_desc(c); merge_top8(R, c);
    }
    const float tmax = R[0];

    // ---- slice g8 = exact 8th-largest of the slice -------------------------
    wave_extract8(R, lane, &sm32[wave * 8]);        // destroys R
    __syncthreads();
    if (wave == 0) {
        float c = (lane < 32) ? sm32[lane] : -INFINITY;
        float m = -INFINITY;
        #pragma unroll
        for (int r = 0; r < TOPK; ++r) {
            m = c; int ml = lane;
            #pragma unroll
            for (int off = 1; off < 64; off <<= 1) {
                float om = __shfl_xor(m, off, 64);
                int   ol = __shfl_xor(ml, off, 64);
                if (om > m || (om == m && ol < ml)) { m = om; ml = ol; }
            }
            if (lane == ml) c = -INFINITY;          // pop
        }
        if (lane == 0) s_g8 = m;                    // 8th extracted = slice g8
    }
    __syncthreads();
    const float g8 = s_g8;

    // ---- index recovery FROM REGISTERS (no reload) -------------------------
    if (tmax >= g8) {
        #pragma unroll
        for (int k = 0; k < NL; ++k) {
            const int idx = tid + (k << 8);
            if (idx < cnt) {
                const unsigned gbase = (unsigned)(2 * (f2start + idx));
                if (arr[k].x >= g8) {
                    int p = atomicAdd(&s_ncand, 1);
                    if (p < CAP) sh_cand[p] = fkey(arr[k].x, gbase);
                }
                if (arr[k].y >= g8) {
                    int p = atomicAdd(&s_ncand, 1);
                    if (p < CAP) sh_cand[p] = fkey(arr[k].y, gbase + 1);
                }
            }
        }
    }
    __syncthreads();
    const int ncand = min(s_ncand, CAP);            // >= 8 by construction

    // ---- slice top-8 keys (wave 0, intra-wave LDS ops need no barrier) -----
    if (wave == 0) {
        for (int it = 0; it < TOPK; ++it) {
            unsigned long long m = 0ull; int ms = 0;
            for (int j = lane; j < ncand; j += 64) {
                unsigned long long x = sh_cand[j];
                if (x > m) { m = x; ms = j; }
            }
            #pragma unroll
            for (int off = 1; off < 64; off <<= 1) {
                unsigned long long om = __shfl_xor(m, off, 64);
                int os = __shfl_xor(ms, off, 64);
                if (om > m) { m = om; ms = os; }
            }
            if (lane == 0) { s_top[it] = m; sh_cand[ms] = 0ull; }
        }
        if (lane < TOPK)
            ws_keys[((size_t)row * NSLICE + s) * TOPK + lane] = s_top[lane];
    }
}

// ============================ Kernel 2 ======================================
// One block per row: merge 4x8 slice keys -> exact row top-8, then fp64
// scoring of the 8 candidates + filtered argmax + swap blend.
__global__ __launch_bounds__(BLOCK) void score_epilogue_kernel(
    const float* __restrict__ delta_grad,   // [B,S,D]
    const float* __restrict__ src_embeds,   // [B,S,D]
    const float* __restrict__ emb,          // [V,D]
    const int*   __restrict__ src_tokens,   // [B,S]
    const unsigned long long* __restrict__ ws_keys,  // [B*S][32]
    const int*   __restrict__ attn,         // [B,S]
    const float* __restrict__ rand_u,       // [B,S]
    int* __restrict__ out)                  // [B,S]
{
    const int row = blockIdx.x;
    const int tid = threadIdx.x;
    const int lane = tid & 63;
    const int wave = tid >> 6;

    __shared__ int    s_cand[TOPK];
    __shared__ double s_scores[TOPK];
    __shared__ double s_pd[4], s_ssq[4];
    __shared__ float  shf[2 * D];                 // dg row | se row (6 KB)

    // ---- stage dg/se rows (float4) + prev_dot/src_sq -----------------------
    {
        const float* dg = delta_grad + (size_t)row * D;
        const float* se = src_embeds + (size_t)row * D;
        double pd = 0.0, ssq = 0.0;
        if (tid < D / 4) {                        // 192 threads, one float4 each
            float4 g = ((const float4*)dg)[tid];
            float4 e = ((const float4*)se)[tid];
            ((float4*)shf)[tid] = g;
            ((float4*)(shf + D))[tid] = e;
            pd  = (double)g.x * e.x + (double)g.y * e.y
                + (double)g.z * e.z + (double)g.w * e.w;
            ssq = (double)e.x * e.x + (double)e.y * e.y
                + (double)e.z * e.z + (double)e.w * e.w;
        }
        #pragma unroll
        for (int off = 32; off; off >>= 1) {
            pd  += __shfl_down(pd, off, 64);
            ssq += __shfl_down(ssq, off, 64);
        }
        if (lane == 0) { s_pd[wave] = pd; s_ssq[wave] = ssq; }
    }

    // ---- merge 32 slice keys -> row top-8 indices (wave 0) -----------------
    if (wave == 0) {
        unsigned long long c = (lane < NSLICE * TOPK)
                             ? ws_keys[(size_t)row * (NSLICE * TOPK) + lane] : 0ull;
        #pragma unroll
        for (int r = 0; r < TOPK; ++r) {
            unsigned long long m = c; int ml = lane;
            #pragma unroll
            for (int off = 1; off < 64; off <<= 1) {
                unsigned long long om = __shfl_xor(m, off, 64);
                int ol = __shfl_xor(ml, off, 64);
                if (om > m) { m = om; ml = ol; }   // keys unique (distinct idx)
            }
            if (lane == ml) c = 0ull;              // pop
            if (lane == 0) s_cand[r] = (int)(~(unsigned int)m);
        }
    }
    __syncthreads();

    // topk_idx *= attention_mask  (mask==0 -> all candidates index 0)
    if (tid == 0 && attn[row] == 0) {
        #pragma unroll
        for (int k = 0; k < TOPK; ++k) s_cand[k] = 0;
    }
    __syncthreads();

    const double prev_dot = s_pd[0] + s_pd[1] + s_pd[2] + s_pd[3];
    const double src_sq   = s_ssq[0] + s_ssq[1] + s_ssq[2] + s_ssq[3];

    // ---- score 8 candidates (2 per wave, fp64) -----------------------------
    #pragma unroll
    for (int kk = 0; kk < 2; ++kk) {
        const int k = 2 * wave + kk;
        const int v = s_cand[k];
        const float* ev = emb + (size_t)v * D;
        double ddg = 0.0, dse = 0.0, dvv = 0.0;
        for (int ii = lane; ii < D; ii += 64) {
            double e = (double)ev[ii];
            ddg += e * (double)shf[ii];
            dse += e * (double)shf[D + ii];
            dvv += e * e;
        }
        #pragma unroll
        for (int off = 32; off; off >>= 1) {
            ddg += __shfl_down(ddg, off, 64);
            dse += __shfl_down(dse, off, 64);
            dvv += __shfl_down(dvv, off, 64);
        }
        if (lane == 0) {
            double sq = src_sq + dvv - 2.0 * dse;
            if (sq < 0.0) sq = 0.0;
            double dn = sqrt(sq + 1e-20);
            s_scores[k] = (ddg - prev_dot) / dn;   // dir_dot_grad / dir_norm
        }
    }
    __syncthreads();

    // ---- filtered argmax + swap blend (thread 0) ---------------------------
    if (tid == 0) {
        const int src_tok = src_tokens[row];
        int best = 0;
        double best_s = 0.0;
        bool found = false;
        #pragma unroll
        for (int k = 0; k < TOPK; ++k) {
            const int v = s_cand[k];
            if (v < NUM_SPECIAL || v == src_tok) continue;   // -inf in reference
            const double sc = s_scores[k];
            // jnp.argmax: lowest index wins ties
            if (!found || sc > best_s || (sc == best_s && v < best)) {
                best = v; best_s = sc; found = true;
            }
        }
        const int adv_flip = found ? best : 0;   // argmax of all -inf -> 0
        const bool no_special = (src_tok >= NUM_SPECIAL);
        const bool swap = (rand_u[row] > 0.7f);  // 1.0 - SWAP_RATIO in f32
        out[row] = (no_special && swap) ? adv_flip : src_tok;
    }
}

extern "C" void kernel_launch(void* const* d_in, const int* in_sizes, int n_in,
                              void* d_out, int out_size, void* d_ws, size_t ws_size,
                              hipStream_t stream) {
    const float* delta_grad = (const float*)d_in[0];
    const float* src_embeds = (const float*)d_in[1];
    const float* emb        = (const float*)d_in[2];
    const int*   src_tokens = (const int*)d_in[3];
    const float* pred_lm    = (const float*)d_in[4];
    const int*   attn       = (const int*)d_in[5];
    const float* randu      = (const float*)d_in[6];
    int* out = (int*)d_out;

    const int BS = in_sizes[3];   // B*S = 2048 positions
    unsigned long long* ws_keys = (unsigned long long*)d_ws;  // BS*32*8B = 512 KB

    topk_slice_kernel<<<BS * NSLICE, BLOCK, 0, stream>>>(pred_lm, ws_keys);
    score_epilogue_kernel<<<BS, BLOCK, 0, stream>>>(delta_grad, src_embeds, emb,
                                                    src_tokens, ws_keys, attn,
                                                    randu, out);
}